// Round 7
// baseline (139.926 us; speedup 1.0000x reference)
//
#include <hip/hip_runtime.h>

typedef __attribute__((ext_vector_type(8))) short bf16x8;
typedef __attribute__((ext_vector_type(4))) float f32x4;
typedef __attribute__((ext_vector_type(8))) unsigned short u16x8;

__device__ __forceinline__ unsigned short f2bf(float f) {
  unsigned int u = __builtin_bit_cast(unsigned int, f);
  u += 0x7fffu + ((u >> 16) & 1u);
  return (unsigned short)(u >> 16);
}
__device__ __forceinline__ float bf2f(unsigned short h) {
  unsigned int u = ((unsigned int)h) << 16;
  return __builtin_bit_cast(float, u);
}

// weight (64,64,3,3) f32 -> wb[p][o][c] bf16 (36864 elems, 73728 B in d_ws)
__global__ __launch_bounds__(256) void prep_w(const float* __restrict__ w,
                                              unsigned short* __restrict__ wb) {
  int t = blockIdx.x * 256 + threadIdx.x;  // < 36864
  int p = t >> 12;
  int rem = t & 4095;
  int o = rem >> 6, c = rem & 63;
  wb[t] = f2bf(w[(o * 64 + c) * 9 + p]);
}

// Block = (b, 4-row band, full width), 1024 thr / 16 waves, 1 block/CU.
// ALL 6 x-rows + 6 guide-rows staged up front -> ONE barrier total.
// Wave tile o16 x m32; weights resident in 72 VGPRs; kern in registers.
__global__ __launch_bounds__(1024, 4) void pac_main(
    const float* __restrict__ x, const float* __restrict__ gin,
    const unsigned short* __restrict__ wb, const float* __restrict__ bias,
    float* __restrict__ out) {
  __shared__ unsigned short xs[6 * 130 * 64];  // 99840 B, XOR-swizzled
  __shared__ unsigned short gs[6 * 130 * 16];  // 24960 B

  const int tid = threadIdx.x;
  const int bid = blockIdx.x;
  const int b = bid & 7;          // batch pinned to one XCD
  const int h0 = (bid >> 3) * 4;
  const int l = tid & 63;
  const int wv = tid >> 6;        // 0..15
  const int l15 = l & 15, lhi = l >> 4;
  const int oq = wv & 3;          // o base = oq*16
  const int mq = wv >> 2;         // m base = mq*32

  // ---- zero boundary cols (0,129) of all 6 slots ----
  u16x8 z = {0, 0, 0, 0, 0, 0, 0, 0};
  if (tid < 96) {
    int slot = tid >> 4, rem = tid & 15;
    int col = (rem & 8) ? 129 : 0, co = rem & 7;
    *reinterpret_cast<u16x8*>(
        &xs[slot * 8320 + col * 64 + ((co ^ (col & 7)) << 3)]) = z;
  } else if (tid < 120) {
    int t2 = tid - 96;
    int slot = t2 >> 2, rem = t2 & 3;
    int col = (rem & 2) ? 129 : 0, cgo = rem & 1;
    *reinterpret_cast<u16x8*>(&gs[slot * 2080 + col * 16 + cgo * 8]) = z;
  }

  // ---- staging helpers (one 256-thread group stages one row) ----
  const int grp = tid >> 8;  // 0..3 (wave-uniform)
  const int t8 = tid & 255;
  f32x4 xv[8];
  float gv[8];
  auto x_issue = [&](int row) {
    const bool vh = (unsigned)row < 128u;
    const int co = t8 >> 5, wq = t8 & 31;
    const float* p =
        x + (((size_t)(b * 64 + co * 8)) * 128 + (vh ? row : 0)) * 128 + wq * 4;
#pragma unroll
    for (int u = 0; u < 8; ++u) {
      f32x4 v = {0.f, 0.f, 0.f, 0.f};
      if (vh) v = *reinterpret_cast<const f32x4*>(p + (size_t)u * 16384);
      xv[u] = v;
    }
  };
  auto x_commit = [&](int slot) {
    const int co = t8 >> 5, wq = t8 & 31;
#pragma unroll
    for (int j = 0; j < 4; ++j) {
      const int col = wq * 4 + j + 1;
      unsigned short t8v[8];
#pragma unroll
      for (int u = 0; u < 8; ++u) t8v[u] = f2bf(xv[u][j]);
      *reinterpret_cast<u16x8*>(
          &xs[slot * 8320 + col * 64 + ((co ^ (col & 7)) << 3)]) =
          *reinterpret_cast<const u16x8*>(t8v);
    }
  };
  auto g_issue = [&](int row) {
    const bool vh = (unsigned)row < 128u;
    const int cgo = t8 >> 7, w = t8 & 127;
    const float* p =
        gin + (((size_t)(b * 16 + cgo * 8)) * 128 + (vh ? row : 0)) * 128 + w;
#pragma unroll
    for (int q = 0; q < 8; ++q) gv[q] = vh ? p[(size_t)q * 16384] : 0.f;
  };
  auto g_commit = [&](int slot) {
    const int cgo = t8 >> 7, w = t8 & 127;
    unsigned short t8v[8];
#pragma unroll
    for (int q = 0; q < 8; ++q) t8v[q] = f2bf(gv[q]);
    *reinterpret_cast<u16x8*>(&gs[slot * 2080 + (w + 1) * 16 + cgo * 8]) =
        *reinterpret_cast<const u16x8*>(t8v);
  };

  // ---- 3 staging passes: x slots 0..5 (rows h0-1..h0+4), g slots 0..5 ----
  x_issue(h0 - 1 + grp);
  x_commit(grp);
  if (grp < 2) x_issue(h0 + 3 + grp); else g_issue(h0 - 1 + (grp - 2));
  if (grp < 2) x_commit(4 + grp);     else g_commit(grp - 2);
  g_issue(h0 + 1 + grp);
  g_commit(2 + grp);

  // ---- weights -> 18 resident frags (72 VGPR) + bias ----
  bf16x8 wfr[9][2];
#pragma unroll
  for (int p = 0; p < 9; ++p)
#pragma unroll
    for (int kk = 0; kk < 2; ++kk) {
      wfr[p][kk] = *reinterpret_cast<const bf16x8*>(
          &wb[(p * 64 + oq * 16 + l15) * 64 + kk * 32 + lhi * 8]);
      asm volatile("" ::"v"(wfr[p][kk]));
    }
  float bv[4];
#pragma unroll
  for (int j = 0; j < 4; ++j) bv[j] = bias[oq * 16 + lhi * 4 + j];

  __syncthreads();  // the ONLY barrier

  // ---- 4 rows, barrier-free, each wave independent ----
#pragma unroll
  for (int r = 0; r < 4; ++r) {
    // kern in registers: lane l -> pixel mq*32+(l&31), cg-half l>>5
    const int pcol = mq * 32 + (l & 31);
    const int half8 = (l >> 5) << 3;
    float kern[9];
    {
      float ctr[8];
      u16x8 cv = *reinterpret_cast<const u16x8*>(
          &gs[(r + 1) * 2080 + (pcol + 1) * 16 + half8]);
#pragma unroll
      for (int e = 0; e < 8; ++e) ctr[e] = bf2f(cv[e]);
#pragma unroll
      for (int di = 0; di < 3; ++di)
#pragma unroll
        for (int dc = 0; dc < 3; ++dc) {
          u16x8 v = *reinterpret_cast<const u16x8*>(
              &gs[(r + di) * 2080 + (pcol + dc) * 16 + half8]);
          float s = 0.f;
#pragma unroll
          for (int e = 0; e < 8; ++e) {
            float d = bf2f(v[e]) - ctr[e];
            s += d * d;
          }
          s += __shfl_xor(s, 32, 64);
          kern[di * 3 + dc] = __expf(-0.5f * s);
        }
    }

    f32x4 acc[2];
    acc[0] = (f32x4){0.f, 0.f, 0.f, 0.f};
    acc[1] = (f32x4){0.f, 0.f, 0.f, 0.f};
#pragma unroll
    for (int di = 0; di < 3; ++di) {
      const int sb = (r + di) * 8320;
#pragma unroll
      for (int dj = 0; dj < 3; ++dj) {
        const int p = di * 3 + dj;
        f32x4 tmp[2];
        tmp[0] = (f32x4){0.f, 0.f, 0.f, 0.f};
        tmp[1] = (f32x4){0.f, 0.f, 0.f, 0.f};
#pragma unroll
        for (int kk = 0; kk < 2; ++kk)
#pragma unroll
          for (int fc = 0; fc < 2; ++fc) {
            const int col = mq * 32 + fc * 16 + l15 + dj;
            bf16x8 xf = *reinterpret_cast<const bf16x8*>(
                &xs[sb + col * 64 + (((kk * 4 + lhi) ^ (col & 7)) << 3)]);
            tmp[fc] = __builtin_amdgcn_mfma_f32_16x16x32_bf16(
                wfr[p][kk], xf, tmp[fc], 0, 0, 0);
          }
        const float km0 = __shfl(kern[p], l15, 64);
        const float km1 = __shfl(kern[p], 16 + l15, 64);
#pragma unroll
        for (int j = 0; j < 4; ++j) {
          acc[0][j] += km0 * tmp[0][j];
          acc[1][j] += km1 * tmp[1][j];
        }
      }
    }

    const int h = h0 + r;
#pragma unroll
    for (int j = 0; j < 4; ++j) {
      const int o = oq * 16 + lhi * 4 + j;
      float* rp = out + (((size_t)(b * 64 + o)) * 128 + h) * 128;
#pragma unroll
      for (int fc = 0; fc < 2; ++fc) {
        float v = acc[fc][j] + bv[j];
        __builtin_nontemporal_store(v > 0.f ? v : 0.f,
                                    &rp[mq * 32 + fc * 16 + l15]);
      }
    }
  }
}

extern "C" void kernel_launch(void* const* d_in, const int* in_sizes, int n_in,
                              void* d_out, int out_size, void* d_ws, size_t ws_size,
                              hipStream_t stream) {
  const float* x = (const float*)d_in[0];
  const float* guide = (const float*)d_in[1];
  const float* weight = (const float*)d_in[2];
  const float* bias = (const float*)d_in[3];
  float* out = (float*)d_out;
  unsigned short* wb = (unsigned short*)d_ws;  // 73728 bytes

  hipLaunchKernelGGL(prep_w, dim3(36864 / 256), dim3(256), 0, stream, weight, wb);
  hipLaunchKernelGGL(pac_main, dim3(256), dim3(1024), 0, stream,
                     x, guide, wb, bias, out);
}